// Round 8
// baseline (265.340 us; speedup 1.0000x reference)
//
// CategoryAttention (softmax over HEADS axis). Round 8.
// vs round 7 (256us): operand-swapped QK^T in pass_a/pass_b (mfma(K,Q) -> lane
// holds 4 CONTIGUOUS k per q): rden loads 32 scalar -> 8x dwordx2; P-writes
// 32x ds_write_b16 -> 8x ds_write_b64 with v_cvt_pk_bf16_f32 packing;
// pass_a stores packed half2x2 (8B) + fast rcp. GEMM/cvt/layout unchanged.
#include <hip/hip_runtime.h>
#include <hip/hip_bf16.h>
#include <hip/hip_fp16.h>

#define DM 1024
#define NH 16
#define HD 64
#define LL 2048

typedef __attribute__((ext_vector_type(8))) short bf16x8;
typedef __attribute__((ext_vector_type(4))) float f32x4;

#define MFMA16(a,b,c) __builtin_amdgcn_mfma_f32_16x16x32_bf16((a),(b),(c),0,0,0)

// async global->LDS, 16B per lane; dst wave-uniform, src per-lane.
#define GL16(g, l) __builtin_amdgcn_global_load_lds( \
    (const __attribute__((address_space(1))) unsigned int*)(g), \
    (__attribute__((address_space(3))) unsigned int*)(l), 16, 0, 0)

__device__ __forceinline__ ushort f2bf(float f) {
  union { float f; unsigned int u; } v; v.f = f;
  unsigned int u = v.u + 0x7fffu + ((v.u >> 16) & 1u);
  return (ushort)(u >> 16);
}

// ---- batched fp32 -> bf16 convert over up to 5 regions ----
__global__ __launch_bounds__(256) void cvt5(const float* __restrict__ s0, ushort* __restrict__ d0, int n0,
                                            const float* __restrict__ s1, ushort* __restrict__ d1, int n1,
                                            const float* __restrict__ s2, ushort* __restrict__ d2, int n2,
                                            const float* __restrict__ s3, ushort* __restrict__ d3, int n3,
                                            const float* __restrict__ s4, ushort* __restrict__ d4, int n4) {
  int i = (blockIdx.x * 256 + threadIdx.x) * 4;
  const float* s; ushort* d;
  if (i < n0) { s = s0; d = d0; }
  else if ((i -= n0) < n1) { s = s1; d = d1; }
  else if ((i -= n1) < n2) { s = s2; d = d2; }
  else if ((i -= n2) < n3) { s = s3; d = d3; }
  else if ((i -= n3) < n4) { s = s4; d = d4; }
  else return;
  float4 v = *(const float4*)(s + i);
  union { ushort u[4]; unsigned long long ll; } o;
  o.u[0] = f2bf(v.x); o.u[1] = f2bf(v.y); o.u[2] = f2bf(v.z); o.u[3] = f2bf(v.w);
  *(unsigned long long*)(d + i) = o.ll;
}

// ---- GEMM: C[m][n] = sum_k A[m][k]*W[n][k] + bias[n] ----
// BM=64 BN=128 BK=64; global_load_lds + XOR swizzle, double-buffered.
template<int MODE>
__global__ __launch_bounds__(256) void gemm_g(const ushort* __restrict__ Ab,
                                              const ushort* __restrict__ Wb,
                                              const float* __restrict__ bias,
                                              float* __restrict__ outf,
                                              ushort* __restrict__ outb) {
  __shared__ ushort lA[2][64][64];
  __shared__ ushort lB[2][128][64];
  const int m0 = blockIdx.x * 64, n0 = blockIdx.y * 128;
  const int t = threadIdx.x;
  const int w = t >> 6, lane = t & 63, lr = lane & 15, lg = lane >> 4;
  const int wm = (w >> 1) * 32, wn = (w & 1) * 64;
  const int lrow8 = lane >> 3;
  const int scol = ((lane & 7) ^ lrow8) * 8;

  f32x4 acc[2][4];
  #pragma unroll
  for (int i = 0; i < 2; ++i)
    #pragma unroll
    for (int j = 0; j < 4; ++j) acc[i][j] = (f32x4){0.f, 0.f, 0.f, 0.f};

  #pragma unroll
  for (int c = 0; c < 2; ++c)
    GL16(Ab + (m0 + w * 16 + c * 8 + lrow8) * DM + scol, &lA[0][w * 16 + c * 8][0]);
  #pragma unroll
  for (int c = 0; c < 4; ++c)
    GL16(Wb + (n0 + w * 32 + c * 8 + lrow8) * DM + scol, &lB[0][w * 32 + c * 8][0]);
  __syncthreads();

  int cur = 0;
  for (int k0 = 0; k0 < DM; k0 += 64) {
    if (k0 + 64 < DM) {
      #pragma unroll
      for (int c = 0; c < 2; ++c)
        GL16(Ab + (m0 + w * 16 + c * 8 + lrow8) * DM + k0 + 64 + scol, &lA[cur ^ 1][w * 16 + c * 8][0]);
      #pragma unroll
      for (int c = 0; c < 4; ++c)
        GL16(Wb + (n0 + w * 32 + c * 8 + lrow8) * DM + k0 + 64 + scol, &lB[cur ^ 1][w * 32 + c * 8][0]);
    }
    #pragma unroll
    for (int ks = 0; ks < 2; ++ks) {
      bf16x8 aF[2], bF[4];
      #pragma unroll
      for (int i = 0; i < 2; ++i)
        aF[i] = *(const bf16x8*)&lA[cur][wm + i * 16 + lr][(((ks * 4 + lg) ^ (lr & 7)) * 8)];
      #pragma unroll
      for (int j = 0; j < 4; ++j)
        bF[j] = *(const bf16x8*)&lB[cur][wn + j * 16 + lr][(((ks * 4 + lg) ^ (lr & 7)) * 8)];
      #pragma unroll
      for (int i = 0; i < 2; ++i)
        #pragma unroll
        for (int j = 0; j < 4; ++j)
          acc[i][j] = MFMA16(aF[i], bF[j], acc[i][j]);
    }
    __syncthreads();
    cur ^= 1;
  }

  #pragma unroll
  for (int i = 0; i < 2; ++i)
    #pragma unroll
    for (int j = 0; j < 4; ++j)
      #pragma unroll
      for (int r = 0; r < 4; ++r) {
        int m = m0 + wm + i * 16 + lg * 4 + r;
        int n = n0 + wn + j * 16 + lr;
        float v = acc[i][j][r] + bias[n];
        if (MODE == 2) {
          outf[m * DM + n] = v;
        } else {
          int b = m >> 11, q = m & 2047, h = n >> 6, d = n & 63;
          if (MODE == 0)
            outb[((b * NH + h) * LL + q) * HD + d] = f2bf(v);
          else
            outb[((b * NH + h) * HD + d) * LL + q] = f2bf(v);
        }
      }
}

// ---- Pass A (MFMA, swapped): rdenH[b][q][k] = 1 / sum_h exp(scale*<Qh,Kh>) ----
// eT = mfma(K,Q): lane holds k = k0 + j*16 + lg*4 + r (contig in r), q = q0 + w*32 + i*16 + lr.
__global__ __launch_bounds__(256) void pass_a_m(const ushort* __restrict__ Qh,
                                                const ushort* __restrict__ Kh,
                                                __half* __restrict__ rdenH) {
  __shared__ ushort lQ[128][72];
  __shared__ ushort lK[128][72];
  const int b = blockIdx.z, q0 = blockIdx.y * 128, k0 = blockIdx.x * 128;
  const int t = threadIdx.x, w = t >> 6, lane = t & 63, lr = lane & 15, lg = lane >> 4;
  const float scale = 0.125f;

  f32x4 acc[2][8];
  #pragma unroll
  for (int i = 0; i < 2; ++i)
    #pragma unroll
    for (int j = 0; j < 8; ++j) acc[i][j] = (f32x4){0.f, 0.f, 0.f, 0.f};

  for (int h = 0; h < NH; ++h) {
    __syncthreads();
    #pragma unroll
    for (int u = 0; u < 4; ++u) {
      int c = u * 256 + t;
      int row = c >> 3, col = (c & 7) * 8;
      *(bf16x8*)&lQ[row][col] = *(const bf16x8*)&Qh[((b * NH + h) * LL + q0 + row) * HD + col];
      *(bf16x8*)&lK[row][col] = *(const bf16x8*)&Kh[((b * NH + h) * LL + k0 + row) * HD + col];
    }
    __syncthreads();
    #pragma unroll
    for (int i = 0; i < 2; ++i) {
      bf16x8 a0 = *(const bf16x8*)&lQ[w * 32 + i * 16 + lr][lg * 8];
      bf16x8 a1 = *(const bf16x8*)&lQ[w * 32 + i * 16 + lr][32 + lg * 8];
      #pragma unroll
      for (int j = 0; j < 8; ++j) {
        bf16x8 b0 = *(const bf16x8*)&lK[j * 16 + lr][lg * 8];
        bf16x8 b1 = *(const bf16x8*)&lK[j * 16 + lr][32 + lg * 8];
        f32x4 e = {0.f, 0.f, 0.f, 0.f};
        e = MFMA16(b0, a0, e);   // swapped: D[k][q]
        e = MFMA16(b1, a1, e);
        #pragma unroll
        for (int r = 0; r < 4; ++r) acc[i][j][r] += __expf(e[r] * scale);
      }
    }
  }

  #pragma unroll
  for (int i = 0; i < 2; ++i)
    #pragma unroll
    for (int j = 0; j < 8; ++j) {
      int q = q0 + w * 32 + i * 16 + lr;
      int k = k0 + j * 16 + lg * 4;
      union { __half2 h2[2]; uint2 u; } pk;
      pk.h2[0] = __floats2half2_rn(__builtin_amdgcn_rcpf(acc[i][j][0]),
                                   __builtin_amdgcn_rcpf(acc[i][j][1]));
      pk.h2[1] = __floats2half2_rn(__builtin_amdgcn_rcpf(acc[i][j][2]),
                                   __builtin_amdgcn_rcpf(acc[i][j][3]));
      *(uint2*)&rdenH[(size_t)(b * LL + q) * LL + k] = pk.u;
    }
}

// ---- Pass B (MFMA, swapped QK): AO[b][q][h*64+d] = sum_k exp(scale*e)*rden * V[k][d] ----
// Block (b,h,128q); 4 waves, wave w owns q in [w*32, w*32+32).
__global__ __launch_bounds__(256) void pass_b_m(const ushort* __restrict__ Qh,
                                                const ushort* __restrict__ Kh,
                                                const ushort* __restrict__ Vt,
                                                const __half* __restrict__ rdenH,
                                                ushort* __restrict__ AO) {
  __shared__ union UQP { ushort q[128][64]; ushort p[4][32][72]; } U;
  __shared__ ushort lK[2][64][64];
  __shared__ ushort lV[2][64][64];
  const int q0 = blockIdx.x * 128, h = blockIdx.y, b = blockIdx.z;
  const int t = threadIdx.x, w = t >> 6, lane = t & 63, lr = lane & 15, lg = lane >> 4;
  const int lrow8 = lane >> 3;
  const int scol = ((lane & 7) ^ lrow8) * 8;
  const int bh = b * NH + h;
  const float scale = 0.125f;

  #pragma unroll
  for (int u = 0; u < 4; ++u) {
    int c = u * 256 + t;
    int row = c >> 3, col = (c & 7) * 8;
    *(bf16x8*)&U.q[row][col] = *(const bf16x8*)&Qh[(bh * LL + q0 + row) * HD + col];
  }
  #pragma unroll
  for (int c = 0; c < 2; ++c) {
    GL16(Kh + (bh * LL + w * 16 + c * 8 + lrow8) * HD + scol, &lK[0][w * 16 + c * 8][0]);
    GL16(Vt + (bh * HD + w * 16 + c * 8 + lrow8) * LL + scol, &lV[0][w * 16 + c * 8][0]);
  }
  __syncthreads();

  bf16x8 aQ0[2], aQ1[2];
  #pragma unroll
  for (int g = 0; g < 2; ++g) {
    aQ0[g] = *(const bf16x8*)&U.q[w * 32 + g * 16 + lr][lg * 8];
    aQ1[g] = *(const bf16x8*)&U.q[w * 32 + g * 16 + lr][32 + lg * 8];
  }
  __syncthreads();   // Q fragment reads complete before any U.p write

  f32x4 accO[2][4];
  #pragma unroll
  for (int g = 0; g < 2; ++g)
    #pragma unroll
    for (int j = 0; j < 4; ++j) accO[g][j] = (f32x4){0.f, 0.f, 0.f, 0.f};

  int cur = 0;
  for (int k0 = 0; k0 < LL; k0 += 64) {
    if (k0 + 64 < LL) {
      #pragma unroll
      for (int c = 0; c < 2; ++c) {
        GL16(Kh + (bh * LL + k0 + 64 + w * 16 + c * 8 + lrow8) * HD + scol, &lK[cur ^ 1][w * 16 + c * 8][0]);
        GL16(Vt + (bh * HD + w * 16 + c * 8 + lrow8) * LL + k0 + 64 + scol, &lV[cur ^ 1][w * 16 + c * 8][0]);
      }
    }
    #pragma unroll
    for (int g = 0; g < 2; ++g) {
      // phase 1 (swapped): eT[j]: lane holds k = k0+j*16+lg*4+r, q = q0+w*32+g*16+lr
      f32x4 e[4];
      #pragma unroll
      for (int j = 0; j < 4; ++j) {
        int krow = j * 16 + lr;
        bf16x8 kf0 = *(const bf16x8*)&lK[cur][krow][((lg ^ (lr & 7)) * 8)];
        bf16x8 kf1 = *(const bf16x8*)&lK[cur][krow][(((4 + lg) ^ (lr & 7)) * 8)];
        e[j] = (f32x4){0.f, 0.f, 0.f, 0.f};
        e[j] = MFMA16(kf0, aQ0[g], e[j]);
        e[j] = MFMA16(kf1, aQ1[g], e[j]);
      }
      // phase 2: p = exp(e*scale)*rden, packed bf16x4 -> one ds_write_b64 per j
      const int qg = q0 + w * 32 + g * 16 + lr;
      const __half* rrow = rdenH + (size_t)(b * LL + qg) * LL + k0;
      #pragma unroll
      for (int j = 0; j < 4; ++j) {
        uint2 rd8 = *(const uint2*)(rrow + j * 16 + lg * 4);
        float2 f0 = __half22float2(*reinterpret_cast<const __half2*>(&rd8.x));
        float2 f1 = __half22float2(*reinterpret_cast<const __half2*>(&rd8.y));
        union { __hip_bfloat162 b2[2]; uint2 u; } pk;
        pk.b2[0] = __float22bfloat162_rn(make_float2(__expf(e[j][0] * scale) * f0.x,
                                                     __expf(e[j][1] * scale) * f0.y));
        pk.b2[1] = __float22bfloat162_rn(make_float2(__expf(e[j][2] * scale) * f1.x,
                                                     __expf(e[j][3] * scale) * f1.y));
        *(uint2*)&U.p[w][g * 16 + lr][j * 16 + lg * 4] = pk.u;
      }
    }
    // phase 3: O += P * Vt
    #pragma unroll
    for (int g = 0; g < 2; ++g) {
      bf16x8 aP0 = *(const bf16x8*)&U.p[w][g * 16 + lr][lg * 8];
      bf16x8 aP1 = *(const bf16x8*)&U.p[w][g * 16 + lr][32 + lg * 8];
      #pragma unroll
      for (int j = 0; j < 4; ++j) {
        int vrow = j * 16 + lr;
        bf16x8 b0 = *(const bf16x8*)&lV[cur][vrow][((lg ^ (lr & 7)) * 8)];
        bf16x8 b1 = *(const bf16x8*)&lV[cur][vrow][(((4 + lg) ^ (lr & 7)) * 8)];
        accO[g][j] = MFMA16(aP0, b0, accO[g][j]);
        accO[g][j] = MFMA16(aP1, b1, accO[g][j]);
      }
    }
    __syncthreads();
    cur ^= 1;
  }

  #pragma unroll
  for (int g = 0; g < 2; ++g)
    #pragma unroll
    for (int j = 0; j < 4; ++j)
      #pragma unroll
      for (int r = 0; r < 4; ++r) {
        int q = q0 + w * 32 + g * 16 + lg * 4 + r;
        int d = j * 16 + lr;
        AO[(b * LL + q) * DM + h * HD + d] = f2bf(accO[g][j][r]);
      }
}

extern "C" void kernel_launch(void* const* d_in, const int* in_sizes, int n_in,
                              void* d_out, int out_size, void* d_ws, size_t ws_size,
                              hipStream_t stream) {
  const float* query = (const float*)d_in[0];
  const float* key   = (const float*)d_in[1];
  const float* value = (const float*)d_in[2];
  const float* Wq_w  = (const float*)d_in[3];
  const float* Wq_b  = (const float*)d_in[4];
  const float* Wk_w  = (const float*)d_in[5];
  const float* Wk_b  = (const float*)d_in[6];
  const float* Wv_w  = (const float*)d_in[7];
  const float* Wv_b  = (const float*)d_in[8];
  const float* Wo_w  = (const float*)d_in[9];
  const float* Wo_b  = (const float*)d_in[10];

  char* ws = (char*)d_ws;
  ushort* Qh  = (ushort*)(ws);                 // [0,8) MB
  ushort* Kh  = (ushort*)(ws + (8u  << 20));   // [8,16)
  ushort* Vt  = (ushort*)(ws + (16u << 20));   // [16,24)
  ushort* AO  = (ushort*)(ws + (24u << 20));   // [24,32) late
  ushort* Wqb = (ushort*)(ws + (24u << 20));   // [24,26) early, dead before AO
  ushort* Wkb = (ushort*)(ws + (26u << 20));   // [26,28)
  ushort* Wvb = (ushort*)(ws + (28u << 20));   // [28,30)
  ushort* qbf = (ushort*)(ws + (32u << 20));   // [32,40) early
  ushort* kbf = (ushort*)(ws + (40u << 20));   // [40,48) early
  ushort* vbf = (ushort*)(ws + (32u << 20));   // reused after gemm Q
  ushort* Wob = (ushort*)(ws + (40u << 20));   // after gemm K
  __half* rdn = (__half*)d_out;                // 16 MB; dead before final GEMM

  const int NA = 2 * LL * DM;
  const int NW = DM * DM;

  cvt5<<<(2 * NA + 3 * NW) / 1024, 256, 0, stream>>>(
      query, qbf, NA, key, kbf, NA, Wq_w, Wqb, NW, Wk_w, Wkb, NW, Wv_w, Wvb, NW);

  dim3 ggrid(64, 8);
  gemm_g<0><<<ggrid, 256, 0, stream>>>(qbf, Wqb, Wq_b, nullptr, Qh);
  gemm_g<0><<<ggrid, 256, 0, stream>>>(kbf, Wkb, Wk_b, nullptr, Kh);

  cvt5<<<(NA + NW) / 1024, 256, 0, stream>>>(
      value, vbf, NA, Wo_w, Wob, NW, nullptr, nullptr, 0, nullptr, nullptr, 0, nullptr, nullptr, 0);

  gemm_g<1><<<ggrid, 256, 0, stream>>>(vbf, Wvb, Wv_b, nullptr, Vt);

  pass_a_m<<<dim3(16, 16, 2), 256, 0, stream>>>(Qh, Kh, rdn);
  pass_b_m<<<dim3(16, NH, 2), 256, 0, stream>>>(Qh, Kh, Vt, rdn, AO);

  gemm_g<2><<<ggrid, 256, 0, stream>>>(AO, Wob, Wo_b, (float*)d_out, nullptr);
}